// Round 2
// baseline (447.135 us; speedup 1.0000x reference)
//
#include <hip/hip_runtime.h>

#define N_NODES 100000
#define N_EDGES 1600000
#define NODE_NF 11
#define EDGE_NF 4
#define H_NF 128
#define SCAN_B 1024
#define NBLK ((N_NODES + SCAN_B - 1) / SCAN_B)   // 98

// Edge-MLP input layout (halves): src@0..10, 0@11, dst@12..22, 0@23,
// attr@24..27, 0@28..31. K=32 MFMA window covers 0..31.
#define K1P 40    // w1h row stride (halves)
#define K2P 136   // h / w2h row stride (halves)
#define EFP 131   // ef row stride (floats) — tier-2 kernel only
#define K1N 160   // node layer-1 padded K

typedef _Float16 half8 __attribute__((ext_vector_type(8)));
typedef float floatx4 __attribute__((ext_vector_type(4)));

__device__ inline half8 load8f(const float* p) {
    float4 x0 = *(const float4*)(p);
    float4 x1 = *(const float4*)(p + 4);
    half8 r;
    r[0]=(_Float16)x0.x; r[1]=(_Float16)x0.y; r[2]=(_Float16)x0.z; r[3]=(_Float16)x0.w;
    r[4]=(_Float16)x1.x; r[5]=(_Float16)x1.y; r[6]=(_Float16)x1.z; r[7]=(_Float16)x1.w;
    return r;
}
__device__ inline half8 zero8() {
    half8 z;
    #pragma unroll
    for (int j = 0; j < 8; ++j) z[j] = (_Float16)0.f;
    return z;
}

// ---------------------------------------------------------------------------
// Fused prep + hist (one launch, flat-index segments).
// ---------------------------------------------------------------------------
#define SEG0 (N_NODES * 12)            // nfh
#define SEG1 (SEG0 + H_NF * K1P)       // w1h
#define SEG2 (SEG1 + H_NF * K2P)       // w2h
#define SEG3 (SEG2 + H_NF * K1N)       // w1nh
#define SEG4 (SEG3 + 16 * K2P + 4)     // w23h + b23
#define SEG5 (SEG4 + N_EDGES)          // hist

__global__ __launch_bounds__(256)
void prep_hist_kernel(const float* __restrict__ nf,
                      const float* __restrict__ eW1,
                      const float* __restrict__ eW2,
                      const float* __restrict__ nW1,
                      const float* __restrict__ nW2,
                      const float* __restrict__ fW,
                      const float* __restrict__ nb2,
                      const float* __restrict__ fb,
                      const int*   __restrict__ edge_index,
                      _Float16* __restrict__ nfh,
                      _Float16* __restrict__ w1h,
                      _Float16* __restrict__ w2h,
                      _Float16* __restrict__ w1nh,
                      _Float16* __restrict__ w23h,
                      float* __restrict__ b23,
                      int* hist)
{
    int i = blockIdx.x * 256 + threadIdx.x;
    if (i < SEG0) {
        int n = i / 12, k = i - n * 12;
        nfh[i] = (k < NODE_NF) ? (_Float16)nf[(size_t)n * NODE_NF + k] : (_Float16)0.f;
    } else if (i < SEG1) {
        int j = i - SEG0;
        int n = j / K1P, k = j - n * K1P;
        float v = 0.f;
        if (k < 11)                 v = eW1[k * H_NF + n];
        else if (k >= 12 && k < 23) v = eW1[(k - 1) * H_NF + n];
        else if (k >= 24 && k < 28) v = eW1[(k - 2) * H_NF + n];
        w1h[j] = (_Float16)v;
    } else if (i < SEG2) {
        int j = i - SEG1;
        int n = j / K2P, k = j - n * K2P;
        w2h[j] = (k < H_NF) ? (_Float16)eW2[k * H_NF + n] : (_Float16)0.f;
    } else if (i < SEG3) {
        int j = i - SEG2;
        int n = j / K1N, k = j - n * K1N;
        float v = 0.f;
        if (k < 11)                  v = nW1[k * H_NF + n];
        else if (k >= 12 && k < 140) v = nW1[(k - 1) * H_NF + n];
        w1nh[j] = (_Float16)v;
    } else if (i < SEG4) {
        int j = i - SEG3;
        if (j < 16 * K2P) {
            int n = j / K2P, k = j - n * K2P;
            float v = 0.f;
            if (n < 4 && k < H_NF) {
                for (int q = 0; q < H_NF; ++q) v += nW2[k * H_NF + q] * fW[q * 4 + n];
            }
            w23h[j] = (_Float16)v;
        } else {
            int o = j - 16 * K2P;
            float v = fb[o];
            for (int q = 0; q < H_NF; ++q) v += nb2[q] * fW[q * 4 + o];
            b23[o] = v;
        }
    } else if (i < SEG5) {
        int e = i - SEG4;
        atomicAdd(&hist[edge_index[e]], 1);
    }
}

__global__ __launch_bounds__(256)
void transpose_w2(const float* __restrict__ W, float* __restrict__ WT) {
    int i = blockIdx.x * 256 + threadIdx.x;
    if (i < H_NF * H_NF) {
        int k = i >> 7, j = i & (H_NF - 1);
        WT[j * H_NF + k] = W[i];
    }
}

// ---------------------------------------------------------------------------
// Scan chain.
// ---------------------------------------------------------------------------
__global__ __launch_bounds__(SCAN_B)
void scan1_kernel(const int* __restrict__ hist, int* starts, int* bsum) {
    __shared__ int buf[SCAN_B];
    int i = blockIdx.x * SCAN_B + threadIdx.x;
    int v = (i < N_NODES) ? hist[i] : 0;
    buf[threadIdx.x] = v;
    __syncthreads();
    for (int off = 1; off < SCAN_B; off <<= 1) {
        int t = (threadIdx.x >= off) ? buf[threadIdx.x - off] : 0;
        __syncthreads();
        buf[threadIdx.x] += t;
        __syncthreads();
    }
    if (i < N_NODES) starts[i] = buf[threadIdx.x] - v;
    if (threadIdx.x == SCAN_B - 1) bsum[blockIdx.x] = buf[SCAN_B - 1];
}

__global__ void scan2_kernel(int* bsum) {
    if (threadIdx.x == 0 && blockIdx.x == 0) {
        int run = 0;
        for (int b = 0; b < NBLK; ++b) { int t = bsum[b]; bsum[b] = run; run += t; }
        bsum[NBLK] = run;
    }
}

__global__ __launch_bounds__(256)
void scan3_kernel(int* starts, int* cursor, const int* __restrict__ bsum) {
    int i = blockIdx.x * 256 + threadIdx.x;
    if (i < N_NODES) {
        int s = starts[i] + bsum[i / SCAN_B];
        starts[i] = s;
        cursor[i] = s;
    }
    if (i == 0) starts[N_NODES] = bsum[NBLK];
}

// ---------------------------------------------------------------------------
// Permute into 16B records: rec[pos] = {row, col, attr01, attr23}.
// ---------------------------------------------------------------------------
__global__ __launch_bounds__(256)
void permrec_kernel(const int* __restrict__ edge_index,
                    const float* __restrict__ edge_attr,
                    int* cursor,
                    int4* __restrict__ rec)
{
    int e = blockIdx.x * 256 + threadIdx.x;
    if (e >= N_EDGES) return;
    int row = edge_index[e];
    int col = edge_index[N_EDGES + e];
    float4 a4 = ((const float4*)edge_attr)[e];
    union { _Float16 h[4]; int2 v; } u;
    u.h[0] = (_Float16)a4.x; u.h[1] = (_Float16)a4.y;
    u.h[2] = (_Float16)a4.z; u.h[3] = (_Float16)a4.w;
    int pos = atomicAdd(&cursor[row], 1);
    rec[pos] = make_int4(row, col, u.v.x, u.v.y);
}

// Tier-2: classic permute (perm only).
__global__ __launch_bounds__(256)
void permute_kernel(const int* __restrict__ edge_index, int* cursor, int* perm) {
    int e = blockIdx.x * 256 + threadIdx.x;
    if (e < N_EDGES) {
        int pos = atomicAdd(&cursor[edge_index[e]], 1);
        perm[pos] = e;
    }
}

// ---------------------------------------------------------------------------
// Edge MLP v6: W2 tile-split across the block's 4 waves.
// v5 held all of W2 in registers (128 VGPRs/wave -> 2 waves/SIMD, occupancy
// 20.8%, 38% dead issue cycles). v6: each wave keeps only 2 of 8 output
// tiles (32 VGPRs), runs layer 1 for its OWN window into a double-buffered
// per-wave Hs arena, then after ONE barrier computes its 2 tiles for ALL 4
// windows of the block and owns the segmented reduction + atomics for its
// 32-feature slice. Same MFMA/atomic counts; +1 barrier and 4x a2 ds_reads
// per 4-window iteration. Registers ~165 -> __launch_bounds__(256,3),
// grid 768 = 3 blocks/CU = 12 waves/CU.
// Hs double-buffer makes one barrier/iter sufficient: reads of buf b at
// iter i precede barrier(i+1) in program order; writes of buf b at iter
// i+2 follow it.
// Barrier-divergence audit: loop condition (base < nwin) is block-uniform;
// no early return before the loop; all 256 threads reach every barrier.
// ---------------------------------------------------------------------------
__global__ __launch_bounds__(256, 3)
void edge_mfma_kernel(const int4* __restrict__ recs,
                      const _Float16* __restrict__ nfh,
                      const _Float16* __restrict__ w1h,
                      const float* __restrict__ eb1,
                      const _Float16* __restrict__ w2h,
                      const float* __restrict__ eb2,
                      float* agg)   // [N_NODES][H_NF]
{
    __shared__ __align__(16) char smem[4 * 1024 + 8 * 4352];
    int t = threadIdx.x;
    int wv = t >> 6, lane = t & 63;
    _Float16* Ain = (_Float16*)(smem + wv * 1024);   // [16][32] halves, own wave
    char* hsbase = smem + 4096;                      // 8 x [16][K2P] halves
    int m = lane & 15, quad = lane >> 4;

    // loop-invariant weight fragments -> registers
    half8 w1f[8], w2f[2][4];
    #pragma unroll
    for (int tile = 0; tile < 8; ++tile)
        w1f[tile] = *(const half8*)(w1h + (tile * 16 + m) * K1P + quad * 8);
    #pragma unroll
    for (int tt = 0; tt < 2; ++tt)
        #pragma unroll
        for (int ks = 0; ks < 4; ++ks)
            w2f[tt][ks] = *(const half8*)(w2h + ((wv * 2 + tt) * 16 + m) * K2P + ks * 32 + quad * 8);
    float b1v[8], b2v[2];
    #pragma unroll
    for (int tile = 0; tile < 8; ++tile) b1v[tile] = eb1[tile * 16 + m];
    #pragma unroll
    for (int tt = 0; tt < 2; ++tt) b2v[tt] = eb2[(wv * 2 + tt) * 16 + m];

    const int nwin = N_EDGES / 16;           // 100000
    const int STRIDE = gridDim.x * 4;
    int base = blockIdx.x * 4;               // block-uniform window base
    int win = base + wv;                     // this wave's own window

    // preamble: rec + nfh gather for the first own window
    int4 rc = make_int4(0, 0, 0, 0);
    if (win < nwin) rc = recs[win * 16 + m];
    int2 g0 = make_int2(0, 0), g1 = g0, g2 = g0;
    if (win < nwin && quad < 2) {
        int node = (quad == 0) ? rc.x : rc.y;
        const int2* p = (const int2*)(nfh + (size_t)node * 12);
        g0 = p[0]; g1 = p[1]; g2 = p[2];
    }

    int buf = 0;
    for (; base < nwin; base += STRIDE, win += STRIDE) {
        bool hw = win < nwin;                // own window valid (wave-uniform)
        int next = win + STRIDE;
        bool hn = next < nwin;
        int4 rcn = make_int4(0, 0, 0, 0);
        if (hn) rcn = recs[next * 16 + m];   // prefetch own next-window rec

        // rows of all 4 windows of this block-iter (L1-cached re-read of recs)
        int rowj[4];
        #pragma unroll
        for (int j = 0; j < 4; ++j)
            rowj[j] = (base + j < nwin) ? ((const int*)recs)[(base + j) * 64 + m * 4] : -1;

        // ---- layer 1 for own window into own Hs arena ----
        if (hw) {
            _Float16* arow = Ain + m * 32;
            if (quad == 0) {                 // src halves 0..11 (11 = 0)
                ((int2*)arow)[0] = g0; ((int2*)arow)[1] = g1; ((int2*)arow)[2] = g2;
            } else if (quad == 1) {          // dst halves 12..23 (23 = 0)
                int2* d = (int2*)(arow + 12);
                d[0] = g0; d[1] = g1; d[2] = g2;
            } else if (quad == 2) {          // attr 24..27, zeros 28..31
                int2* d = (int2*)(arow + 24);
                d[0] = make_int2(rc.z, rc.w);
                d[1] = make_int2(0, 0);
            }
            half8 a1 = *(const half8*)(Ain + m * 32 + quad * 8);  // lgkm-ordered
            _Float16* Hs = (_Float16*)(hsbase + (buf * 4 + wv) * 4352);
            #pragma unroll
            for (int tile = 0; tile < 8; ++tile) {
                floatx4 c = {0.f, 0.f, 0.f, 0.f};
                c = __builtin_amdgcn_mfma_f32_16x16x32_f16(a1, w1f[tile], c, 0, 0, 0);
                int n = tile * 16 + m;
                #pragma unroll
                for (int r = 0; r < 4; ++r)
                    Hs[(quad * 4 + r) * K2P + n] = (_Float16)fmaxf(c[r] + b1v[tile], 0.f);
            }
        }
        __syncthreads();

        // ---- layer 2: this wave's 2 output tiles for ALL 4 windows ----
        float vals[4][8];
        #pragma unroll
        for (int j = 0; j < 4; ++j) {
            if (base + j < nwin) {
                const _Float16* Hj = (const _Float16*)(hsbase + (buf * 4 + j) * 4352);
                half8 a2[4];
                #pragma unroll
                for (int ks = 0; ks < 4; ++ks)
                    a2[ks] = *(const half8*)(Hj + m * K2P + ks * 32 + quad * 8);
                #pragma unroll
                for (int tt = 0; tt < 2; ++tt) {
                    floatx4 c = {0.f, 0.f, 0.f, 0.f};
                    #pragma unroll
                    for (int ks = 0; ks < 4; ++ks)
                        c = __builtin_amdgcn_mfma_f32_16x16x32_f16(a2[ks], w2f[tt][ks], c, 0, 0, 0);
                    #pragma unroll
                    for (int r = 0; r < 4; ++r)
                        vals[j][tt * 4 + r] = fmaxf(c[r] + b2v[tt], 0.f);
                }
            }
        }

        // ---- pipelined nfh gather for next own window (rcn has arrived) ----
        int2 n0 = make_int2(0, 0), n1 = n0, n2 = n0;
        if (hn && quad < 2) {
            int node = (quad == 0) ? rcn.x : rcn.y;
            const int2* p = (const int2*)(nfh + (size_t)node * 12);
            n0 = p[0]; n1 = p[1]; n2 = p[2];
        }

        // ---- segmented reduction per window, this wave's feature slice ----
        #pragma unroll
        for (int j = 0; j < 4; ++j) {
            if (base + j < nwin) {
                int row = rowj[j];
                int rprev = __shfl(row, lane - 1);
                bool bi = (lane < 16) && (m == 0 || rprev != row);
                unsigned long long bm = __ballot(bi);
                unsigned mk = (unsigned)(bm & 0xFFFFull);
                int er0 = __shfl(row, quad * 4 + 0);
                int er1 = __shfl(row, quad * 4 + 1);
                int er2 = __shfl(row, quad * 4 + 2);
                int er3 = __shfl(row, quad * 4 + 3);
                while (mk) {
                    int start = __builtin_ctz(mk);   // wave-uniform
                    mk &= mk - 1;
                    int srow = __shfl(row, start);
                    float s0 = 0.f, s1 = 0.f;
                    if (er0 == srow) { s0 += vals[j][0]; s1 += vals[j][4]; }
                    if (er1 == srow) { s0 += vals[j][1]; s1 += vals[j][5]; }
                    if (er2 == srow) { s0 += vals[j][2]; s1 += vals[j][6]; }
                    if (er3 == srow) { s0 += vals[j][3]; s1 += vals[j][7]; }
                    s0 += __shfl_xor(s0, 16); s0 += __shfl_xor(s0, 32);
                    s1 += __shfl_xor(s1, 16); s1 += __shfl_xor(s1, 32);
                    if (quad == 0) {
                        unsafeAtomicAdd(&agg[(size_t)srow * H_NF + (wv * 2 + 0) * 16 + m], s0);
                        unsafeAtomicAdd(&agg[(size_t)srow * H_NF + (wv * 2 + 1) * 16 + m], s1);
                    }
                }
            }
        }

        rc = rcn; g0 = n0; g1 = n1; g2 = n2;
        buf ^= 1;
    }
}

// ---------------------------------------------------------------------------
// Tier-2 edge kernel: in-kernel gather via perm (no rec buffer). LDS reduction.
// ---------------------------------------------------------------------------
#define G_W1      0
#define G_W2      10240
#define G_ARENA   45056
#define G_ARENA_SZ 8448
#define G_TOTAL   (G_ARENA + 4 * G_ARENA_SZ)

__global__ __launch_bounds__(256, 2)
void edge_mfma_gather_kernel(const _Float16* __restrict__ nfh,
                             const int*   __restrict__ edge_index,
                             const float* __restrict__ edge_attr,
                             const _Float16* __restrict__ w1h,
                             const float* __restrict__ eb1,
                             const _Float16* __restrict__ w2h,
                             const float* __restrict__ eb2,
                             const int*   __restrict__ perm,
                             float* agg)
{
    __shared__ __align__(16) char smem[G_TOTAL];
    _Float16* W1s = (_Float16*)(smem + G_W1);
    _Float16* W2s = (_Float16*)(smem + G_W2);
    int t = threadIdx.x;
    {
        const float4* g1 = (const float4*)w1h;
        float4* s1 = (float4*)W1s;
        for (int i = t; i < 640; i += 256) s1[i] = g1[i];
        const float4* g2 = (const float4*)w2h;
        float4* s2 = (float4*)W2s;
        for (int i = t; i < 2176; i += 256) s2[i] = g2[i];
    }
    __syncthreads();

    int wv = t >> 6, lane = t & 63;
    char* arena = smem + G_ARENA + wv * G_ARENA_SZ;
    _Float16* Ain  = (_Float16*)arena;
    _Float16* Hs   = (_Float16*)(arena + 1280);
    float*    efS  = (float*)arena;
    int*      rowsS = (int*)(arena + 8384);

    int m = lane & 15, quad = lane >> 4;
    int el = lane & 15, grp = lane >> 4;
    _Float16* arow = Ain + el * K1P;

    float b1v[8], b2v[8];
    #pragma unroll
    for (int tile = 0; tile < 8; ++tile) {
        b1v[tile] = eb1[tile * 16 + m];
        b2v[tile] = eb2[tile * 16 + m];
    }

    const int nwin = N_EDGES / 16;
    for (int win = blockIdx.x * 4 + wv; win < nwin; win += gridDim.x * 4) {
        int e = perm[win * 16 + el];
        if (grp < 2) {
            int node = edge_index[grp * N_EDGES + e];
            const int2* p = (const int2*)(nfh + (size_t)node * 12);
            int2 x0 = p[0], x1 = p[1], x2 = p[2];
            char* dst = (char*)(arow + grp * 12);
            *(int2*)(dst) = x0; *(int2*)(dst + 8) = x1; *(int2*)(dst + 16) = x2;
        } else if (grp == 2) {
            float4 a4 = ((const float4*)edge_attr)[e];
            arow[24] = (_Float16)a4.x; arow[25] = (_Float16)a4.y;
            arow[26] = (_Float16)a4.z; arow[27] = (_Float16)a4.w;
        } else {
            rowsS[el] = edge_index[e];
            *(int2*)((char*)arow + 56) = make_int2(0, 0);
        }

        half8 a1 = *(const half8*)(Ain + m * K1P + quad * 8);
        #pragma unroll
        for (int tile = 0; tile < 8; ++tile) {
            half8 b = *(const half8*)(W1s + (tile * 16 + m) * K1P + quad * 8);
            floatx4 c = {0.f, 0.f, 0.f, 0.f};
            c = __builtin_amdgcn_mfma_f32_16x16x32_f16(a1, b, c, 0, 0, 0);
            int n = tile * 16 + m;
            #pragma unroll
            for (int r = 0; r < 4; ++r)
                Hs[(quad * 4 + r) * K2P + n] = (_Float16)fmaxf(c[r] + b1v[tile], 0.f);
        }
        half8 a2[4];
        #pragma unroll
        for (int ks = 0; ks < 4; ++ks)
            a2[ks] = *(const half8*)(Hs + m * K2P + ks * 32 + quad * 8);
        #pragma unroll
        for (int tile = 0; tile < 8; ++tile) {
            floatx4 c = {0.f, 0.f, 0.f, 0.f};
            #pragma unroll
            for (int ks = 0; ks < 4; ++ks) {
                half8 b = *(const half8*)(W2s + (tile * 16 + m) * K2P + ks * 32 + quad * 8);
                c = __builtin_amdgcn_mfma_f32_16x16x32_f16(a2[ks], b, c, 0, 0, 0);
            }
            #pragma unroll
            for (int r = 0; r < 4; ++r)
                efS[(quad * 4 + r) * EFP + tile * 16 + m] = fmaxf(c[r] + b2v[tile], 0.f);
        }

        int f = lane;
        int cur = rowsS[0];
        float acc0 = efS[f], acc1 = efS[64 + f];
        #pragma unroll 1
        for (int i = 1; i < 16; ++i) {
            int r = rowsS[i];
            float v0 = efS[i * EFP + f];
            float v1 = efS[i * EFP + 64 + f];
            if (r != cur) {
                unsafeAtomicAdd(&agg[(size_t)cur * H_NF + f], acc0);
                unsafeAtomicAdd(&agg[(size_t)cur * H_NF + 64 + f], acc1);
                acc0 = v0; acc1 = v1; cur = r;
            } else { acc0 += v0; acc1 += v1; }
        }
        unsafeAtomicAdd(&agg[(size_t)cur * H_NF + f], acc0);
        unsafeAtomicAdd(&agg[(size_t)cur * H_NF + 64 + f], acc1);
    }
}

// ---------------------------------------------------------------------------
// Fused node pipeline, persistent, epilogue bias.
// ---------------------------------------------------------------------------
#define N_W1    0                         // 128*160*2 = 40960
#define N_W23   40960                     // 16*136*2  = 4352 -> 45312
#define N_HS    45312                     // + 4*4352 -> 62720

__global__ __launch_bounds__(256, 2)
void node_mfma_kernel(const float* __restrict__ node_feats,
                      const float* __restrict__ agg,
                      const _Float16* __restrict__ w1nh,
                      const float* __restrict__ nb1,
                      const _Float16* __restrict__ w23h,
                      const float* __restrict__ b23,
                      float* __restrict__ out)
{
    __shared__ __align__(16) char smem[N_HS + 4 * 4352];
    _Float16* W1N  = (_Float16*)(smem + N_W1);
    _Float16* W23s = (_Float16*)(smem + N_W23);
    int t = threadIdx.x;
    {
        const float4* g1 = (const float4*)w1nh;
        float4* s1 = (float4*)W1N;
        for (int i = t; i < 2560; i += 256) s1[i] = g1[i];
        const float4* g2 = (const float4*)w23h;
        float4* s2 = (float4*)W23s;
        for (int i = t; i < 272; i += 256) s2[i] = g2[i];
    }
    __syncthreads();

    int wv = t >> 6, lane = t & 63;
    int m = lane & 15, quad = lane >> 4;
    _Float16* HsW = (_Float16*)(smem + N_HS + wv * 4352);
    const int ntile = (N_NODES + 63) / 64;   // 1563

    float nb1v[8];
    #pragma unroll
    for (int tile = 0; tile < 8; ++tile) nb1v[tile] = nb1[tile * 16 + m];
    float b23v = (m < 4) ? b23[m] : 0.f;

    for (int ti = blockIdx.x; ti < ntile; ti += gridDim.x) {
        int nb = (ti * 4 + wv) * 16;
        if (nb >= N_NODES) continue;
        int nodeA = nb + m;
        if (nodeA >= N_NODES) nodeA = N_NODES - 1;
        const float* ag  = agg + (size_t)nodeA * H_NF;
        const float* nfp = node_feats + (size_t)nodeA * NODE_NF;

        half8 afr[5];
        if (quad == 0) {
            half8 r;
            #pragma unroll
            for (int j = 0; j < 8; ++j) r[j] = (_Float16)nfp[j];
            afr[0] = r;
            afr[4] = load8f(ag + 116);
        } else if (quad == 1) {
            half8 r;
            r[0] = (_Float16)nfp[8]; r[1] = (_Float16)nfp[9];
            r[2] = (_Float16)nfp[10]; r[3] = (_Float16)0.f;
            float4 x = *(const float4*)(ag);
            r[4] = (_Float16)x.x; r[5] = (_Float16)x.y;
            r[6] = (_Float16)x.z; r[7] = (_Float16)x.w;
            afr[0] = r;
            float4 y = *(const float4*)(ag + 124);
            half8 s = zero8();
            s[0] = (_Float16)y.x; s[1] = (_Float16)y.y;
            s[2] = (_Float16)y.z; s[3] = (_Float16)y.w;
            afr[4] = s;
        } else if (quad == 2) {
            afr[0] = load8f(ag + 4);
            afr[4] = zero8();
        } else {
            afr[0] = load8f(ag + 12);
            afr[4] = zero8();
        }
        afr[1] = load8f(ag + 20 + 8 * quad);
        afr[2] = load8f(ag + 52 + 8 * quad);
        afr[3] = load8f(ag + 84 + 8 * quad);

        #pragma unroll
        for (int tile = 0; tile < 8; ++tile) {
            floatx4 c = {0.f, 0.f, 0.f, 0.f};
            #pragma unroll
            for (int ks = 0; ks < 5; ++ks) {
                half8 b = *(const half8*)(W1N + (tile * 16 + m) * K1N + ks * 32 + quad * 8);
                c = __builtin_amdgcn_mfma_f32_16x16x32_f16(afr[ks], b, c, 0, 0, 0);
            }
            #pragma unroll
            for (int r = 0; r < 4; ++r)
                HsW[(quad * 4 + r) * K2P + tile * 16 + m] = (_Float16)fmaxf(c[r] + nb1v[tile], 0.f);
        }

        half8 a2[4];
        #pragma unroll
        for (int ks = 0; ks < 4; ++ks)
            a2[ks] = *(const half8*)(HsW + m * K2P + ks * 32 + quad * 8);
        floatx4 c23 = {0.f, 0.f, 0.f, 0.f};
        #pragma unroll
        for (int ks = 0; ks < 4; ++ks) {
            half8 b = *(const half8*)(W23s + m * K2P + ks * 32 + quad * 8);
            c23 = __builtin_amdgcn_mfma_f32_16x16x32_f16(a2[ks], b, c23, 0, 0, 0);
        }
        if (m < 4) {
            #pragma unroll
            for (int r = 0; r < 4; ++r) {
                int node = nb + quad * 4 + r;
                if (node < N_NODES) out[node * 4 + m] = c23[r] + b23v;
            }
        }
    }
}

// ---------------------------------------------------------------------------
// Tier-3 fp32 fallback.
// ---------------------------------------------------------------------------
__global__ __launch_bounds__(256)
void edge_kernel_atomic(const float* __restrict__ node_feats,
                        const int*   __restrict__ edge_index,
                        const float* __restrict__ edge_attr,
                        const float* __restrict__ eW1,
                        const float* __restrict__ eb1,
                        const float* __restrict__ W2T,
                        const float* __restrict__ eb2,
                        float* agg)
{
    int e = blockIdx.x * 256 + threadIdx.x;
    if (e >= N_EDGES) return;
    int row = edge_index[e];
    int col = edge_index[N_EDGES + e];
    float h[H_NF];
    #pragma unroll
    for (int j = 0; j < H_NF; ++j) h[j] = eb1[j];
    const float* srcp = node_feats + (size_t)row * NODE_NF;
    #pragma unroll 1
    for (int k = 0; k < NODE_NF; ++k) {
        float x = srcp[k];
        const float* w = eW1 + k * H_NF;
        #pragma unroll
        for (int j = 0; j < H_NF; ++j) h[j] = fmaf(x, w[j], h[j]);
    }
    const float* dstp = node_feats + (size_t)col * NODE_NF;
    #pragma unroll 1
    for (int k = 0; k < NODE_NF; ++k) {
        float x = dstp[k];
        const float* w = eW1 + (NODE_NF + k) * H_NF;
        #pragma unroll
        for (int j = 0; j < H_NF; ++j) h[j] = fmaf(x, w[j], h[j]);
    }
    float4 at = ((const float4*)edge_attr)[e];
    float av[EDGE_NF] = {at.x, at.y, at.z, at.w};
    #pragma unroll
    for (int k = 0; k < EDGE_NF; ++k) {
        float x = av[k];
        const float* w = eW1 + (2 * NODE_NF + k) * H_NF;
        #pragma unroll
        for (int j = 0; j < H_NF; ++j) h[j] = fmaf(x, w[j], h[j]);
    }
    #pragma unroll
    for (int j = 0; j < H_NF; ++j) h[j] = fmaxf(h[j], 0.f);
    #pragma unroll 1
    for (int j0 = 0; j0 < H_NF; j0 += 8) {
        float acc[8];
        #pragma unroll
        for (int jj = 0; jj < 8; ++jj) acc[jj] = eb2[j0 + jj];
        #pragma unroll
        for (int k = 0; k < H_NF; ++k) {
            float x = h[k];
            #pragma unroll
            for (int jj = 0; jj < 8; ++jj)
                acc[jj] = fmaf(x, W2T[(j0 + jj) * H_NF + k], acc[jj]);
        }
        #pragma unroll
        for (int jj = 0; jj < 8; ++jj)
            unsafeAtomicAdd(&agg[(size_t)row * H_NF + j0 + jj], fmaxf(acc[jj], 0.f));
    }
}

__global__ __launch_bounds__(256)
void node_kernel1(const float* __restrict__ node_feats, float* agg_nh,
                  const float* __restrict__ nW1, const float* __restrict__ nb1)
{
    int n = blockIdx.x * 256 + threadIdx.x;
    if (n >= N_NODES) return;
    float acc[H_NF];
    #pragma unroll
    for (int j = 0; j < H_NF; ++j) acc[j] = nb1[j];
    const float* nfp = node_feats + (size_t)n * NODE_NF;
    #pragma unroll 1
    for (int k = 0; k < NODE_NF; ++k) {
        float x = nfp[k];
        const float* w = nW1 + k * H_NF;
        #pragma unroll
        for (int j = 0; j < H_NF; ++j) acc[j] = fmaf(x, w[j], acc[j]);
    }
    const float4* ap = (const float4*)(agg_nh + (size_t)n * H_NF);
    #pragma unroll 1
    for (int k4 = 0; k4 < H_NF / 4; ++k4) {
        float4 x = ap[k4];
        const float* w0 = nW1 + (NODE_NF + k4 * 4 + 0) * H_NF;
        const float* w1 = nW1 + (NODE_NF + k4 * 4 + 1) * H_NF;
        const float* w2 = nW1 + (NODE_NF + k4 * 4 + 2) * H_NF;
        const float* w3 = nW1 + (NODE_NF + k4 * 4 + 3) * H_NF;
        #pragma unroll
        for (int j = 0; j < H_NF; ++j) {
            acc[j] = fmaf(x.x, w0[j], acc[j]);
            acc[j] = fmaf(x.y, w1[j], acc[j]);
            acc[j] = fmaf(x.z, w2[j], acc[j]);
            acc[j] = fmaf(x.w, w3[j], acc[j]);
        }
    }
    float* op = agg_nh + (size_t)n * H_NF;
    #pragma unroll
    for (int j4 = 0; j4 < H_NF / 4; ++j4) {
        float4 o = make_float4(fmaxf(acc[j4*4+0], 0.f), fmaxf(acc[j4*4+1], 0.f),
                               fmaxf(acc[j4*4+2], 0.f), fmaxf(acc[j4*4+3], 0.f));
        ((float4*)op)[j4] = o;
    }
}

__global__ __launch_bounds__(256)
void node_kernel2(const float* __restrict__ nh, const float* __restrict__ nW2,
                  const float* __restrict__ nb2, const float* __restrict__ fW,
                  const float* __restrict__ fb, float* __restrict__ out)
{
    int n = blockIdx.x * 256 + threadIdx.x;
    if (n >= N_NODES) return;
    float acc[H_NF];
    #pragma unroll
    for (int j = 0; j < H_NF; ++j) acc[j] = nb2[j];
    const float4* hp = (const float4*)(nh + (size_t)n * H_NF);
    #pragma unroll 1
    for (int k4 = 0; k4 < H_NF / 4; ++k4) {
        float4 x = hp[k4];
        const float* w0 = nW2 + (k4 * 4 + 0) * H_NF;
        const float* w1 = nW2 + (k4 * 4 + 1) * H_NF;
        const float* w2 = nW2 + (k4 * 4 + 2) * H_NF;
        const float* w3 = nW2 + (k4 * 4 + 3) * H_NF;
        #pragma unroll
        for (int j = 0; j < H_NF; ++j) {
            acc[j] = fmaf(x.x, w0[j], acc[j]);
            acc[j] = fmaf(x.y, w1[j], acc[j]);
            acc[j] = fmaf(x.z, w2[j], acc[j]);
            acc[j] = fmaf(x.w, w3[j], acc[j]);
        }
    }
    float o0 = fb[0], o1 = fb[1], o2 = fb[2], o3 = fb[3];
    #pragma unroll
    for (int j = 0; j < H_NF; ++j) {
        o0 = fmaf(acc[j], fW[j * 4 + 0], o0);
        o1 = fmaf(acc[j], fW[j * 4 + 1], o1);
        o2 = fmaf(acc[j], fW[j * 4 + 2], o2);
        o3 = fmaf(acc[j], fW[j * 4 + 3], o3);
    }
    ((float4*)out)[n] = make_float4(o0, o1, o2, o3);
}

extern "C" void kernel_launch(void* const* d_in, const int* in_sizes, int n_in,
                              void* d_out, int out_size, void* d_ws, size_t ws_size,
                              hipStream_t stream)
{
    const float* node_feats = (const float*)d_in[0];
    const int*   edge_index = (const int*)d_in[1];
    const float* edge_attr  = (const float*)d_in[2];
    const float* eW1 = (const float*)d_in[3];
    const float* eb1 = (const float*)d_in[4];
    const float* eW2 = (const float*)d_in[5];
    const float* eb2 = (const float*)d_in[6];
    const float* nW1 = (const float*)d_in[7];
    const float* nb1 = (const float*)d_in[8];
    const float* nW2 = (const float*)d_in[9];
    const float* nb2 = (const float*)d_in[10];
    const float* fW  = (const float*)d_in[11];
    const float* fb  = (const float*)d_in[12];
    float* out = (float*)d_out;

    // ---- workspace carve-up (256B aligned). agg+hist adjacent -> ONE memset.
    size_t off = 0;
    auto carve = [&](size_t bytes) {
        void* p = (char*)d_ws + off;
        off = (off + bytes + 255) & ~(size_t)255;
        return p;
    };
    float*     agg    = (float*)carve((size_t)N_NODES * H_NF * sizeof(float)); // 51.2 MB
    int*       hist   = (int*)  carve((size_t)N_NODES * sizeof(int));
    size_t zero_bytes = off;   // agg + hist (contiguous from d_ws base)
    int*       starts = (int*)  carve((size_t)(N_NODES + 1) * sizeof(int));
    int*       cursor = (int*)  carve((size_t)N_NODES * sizeof(int));
    int*       bsum   = (int*)  carve((size_t)(NBLK + 1) * sizeof(int));
    _Float16*  nfh    = (_Float16*)carve((size_t)N_NODES * 12 * sizeof(_Float16)); // 2.4 MB
    _Float16*  w1h    = (_Float16*)carve((size_t)H_NF * K1P * sizeof(_Float16));
    _Float16*  w2h    = (_Float16*)carve((size_t)H_NF * K2P * sizeof(_Float16));
    _Float16*  w1nh   = (_Float16*)carve((size_t)H_NF * K1N * sizeof(_Float16));
    _Float16*  w23h   = (_Float16*)carve((size_t)16 * K2P * sizeof(_Float16));
    float*     b23    = (float*)carve(4 * sizeof(float));
    int*       perm   = (int*)  carve((size_t)N_EDGES * sizeof(int));          // tier-2 only
    size_t required_t2 = off;
    int4*      rec    = (int4*) carve((size_t)N_EDGES * sizeof(int4));         // 25.6 MB
    size_t required_t1 = off;

    if (ws_size >= required_t2) {
        hipMemsetAsync(d_ws, 0, zero_bytes, stream);
        prep_hist_kernel<<<(SEG5 + 255) / 256, 256, 0, stream>>>(
            node_feats, eW1, eW2, nW1, nW2, fW, nb2, fb, edge_index,
            nfh, w1h, w2h, w1nh, w23h, b23, hist);
        scan1_kernel<<<NBLK, SCAN_B, 0, stream>>>(hist, starts, bsum);
        scan2_kernel<<<1, 64, 0, stream>>>(bsum);
        scan3_kernel<<<(N_NODES + 255) / 256, 256, 0, stream>>>(starts, cursor, bsum);

        if (ws_size >= required_t1) {
            permrec_kernel<<<(N_EDGES + 255) / 256, 256, 0, stream>>>(
                edge_index, edge_attr, cursor, rec);
            // 768 blocks = 3/CU (12 waves/CU at launch_bounds(256,3))
            edge_mfma_kernel<<<768, 256, 0, stream>>>(
                rec, nfh, w1h, eb1, w2h, eb2, agg);
        } else {
            permute_kernel<<<(N_EDGES + 255) / 256, 256, 0, stream>>>(edge_index, cursor, perm);
            edge_mfma_gather_kernel<<<512, 256, 0, stream>>>(
                nfh, edge_index, edge_attr, w1h, eb1, w2h, eb2, perm, agg);
        }
        node_mfma_kernel<<<512, 256, 0, stream>>>(
            node_feats, agg, w1nh, nb1, w23h, b23, out);
    } else {
        // tier 3: fp32 atomic scatter path
        float* agg_fb = (float*)d_ws;
        float* W2T_fb = (float*)((char*)d_ws + (size_t)N_NODES * H_NF * sizeof(float));
        transpose_w2<<<(H_NF * H_NF + 255) / 256, 256, 0, stream>>>(eW2, W2T_fb);
        hipMemsetAsync(agg_fb, 0, (size_t)N_NODES * H_NF * sizeof(float), stream);
        edge_kernel_atomic<<<(N_EDGES + 255) / 256, 256, 0, stream>>>(
            node_feats, edge_index, edge_attr, eW1, eb1, W2T_fb, eb2, agg_fb);
        node_kernel1<<<(N_NODES + 255) / 256, 256, 0, stream>>>(node_feats, agg_fb, nW1, nb1);
        node_kernel2<<<(N_NODES + 255) / 256, 256, 0, stream>>>(agg_fb, nW2, nb2, fW, fb, out);
    }
}

// Round 4
// 412.451 us; speedup vs baseline: 1.0841x; 1.0841x over previous
//
#include <hip/hip_runtime.h>

#define N_NODES 100000
#define N_EDGES 1600000
#define NODE_NF 11
#define EDGE_NF 4
#define H_NF 128
#define SCAN_B 1024
#define NBLK ((N_NODES + SCAN_B - 1) / SCAN_B)   // 98

// Edge-MLP input layout (halves): src@0..10, 0@11, dst@12..22, 0@23,
// attr@24..27, bias-one@28, 0@29..31. K=32 MFMA window covers 0..31.
// w1h row n: W1^T[n][k] with eb1[n] planted at k=28 (bias via MFMA).
// w2h row n: PERMUTED k-layout: position kappa=(ks,q,j) holds
// W2[32ks + 16*(j>>2) + 4q + (j&3)][n]  (see edge kernel v7b notes).
#define K1P 40    // w1h row stride (halves)
#define K2P 136   // h / w2h row stride (halves)
#define EFP 131   // ef row stride (floats) — tier-2 kernel only
#define K1N 160   // node layer-1 padded K

typedef _Float16 half8 __attribute__((ext_vector_type(8)));
typedef float floatx4 __attribute__((ext_vector_type(4)));

__device__ inline half8 load8f(const float* p) {
    float4 x0 = *(const float4*)(p);
    float4 x1 = *(const float4*)(p + 4);
    half8 r;
    r[0]=(_Float16)x0.x; r[1]=(_Float16)x0.y; r[2]=(_Float16)x0.z; r[3]=(_Float16)x0.w;
    r[4]=(_Float16)x1.x; r[5]=(_Float16)x1.y; r[6]=(_Float16)x1.z; r[7]=(_Float16)x1.w;
    return r;
}
__device__ inline half8 zero8() {
    half8 z;
    #pragma unroll
    for (int j = 0; j < 8; ++j) z[j] = (_Float16)0.f;
    return z;
}

// ---------------------------------------------------------------------------
// Fused prep + hist (one launch, flat-index segments).
// ---------------------------------------------------------------------------
#define SEG0 (N_NODES * 12)            // nfh
#define SEG1 (SEG0 + H_NF * K1P)       // w1h
#define SEG2 (SEG1 + H_NF * K2P)       // w2h
#define SEG3 (SEG2 + H_NF * K1N)       // w1nh
#define SEG4 (SEG3 + 16 * K2P + 4)     // w23h + b23
#define SEG5 (SEG4 + N_EDGES)          // hist

__global__ __launch_bounds__(256)
void prep_hist_kernel(const float* __restrict__ nf,
                      const float* __restrict__ eW1,
                      const float* __restrict__ eb1,
                      const float* __restrict__ eW2,
                      const float* __restrict__ nW1,
                      const float* __restrict__ nW2,
                      const float* __restrict__ fW,
                      const float* __restrict__ nb2,
                      const float* __restrict__ fb,
                      const int*   __restrict__ edge_index,
                      _Float16* __restrict__ nfh,
                      _Float16* __restrict__ w1h,
                      _Float16* __restrict__ w2h,
                      _Float16* __restrict__ w1nh,
                      _Float16* __restrict__ w23h,
                      float* __restrict__ b23,
                      int* hist)
{
    int i = blockIdx.x * 256 + threadIdx.x;
    if (i < SEG0) {
        int n = i / 12, k = i - n * 12;
        nfh[i] = (k < NODE_NF) ? (_Float16)nf[(size_t)n * NODE_NF + k] : (_Float16)0.f;
    } else if (i < SEG1) {
        int j = i - SEG0;
        int n = j / K1P, k = j - n * K1P;
        float v = 0.f;
        if (k < 11)                 v = eW1[k * H_NF + n];
        else if (k >= 12 && k < 23) v = eW1[(k - 1) * H_NF + n];
        else if (k >= 24 && k < 28) v = eW1[(k - 2) * H_NF + n];
        else if (k == 28)           v = eb1[n];      // bias via k=28 slot
        w1h[j] = (_Float16)v;
    } else if (i < SEG2) {
        int j = i - SEG1;
        int n = j / K2P, k = j - n * K2P;   // k = fragment position kappa
        float v = 0.f;
        if (k < H_NF) {
            // kappa = ks*32 + q*8 + jj  ->  actual W2 row:
            // ka = 32*ks + 16*(jj>>2) + 4*q + (jj&3)   (bijective bit shuffle)
            int ks = k >> 5, rem = k & 31, q = rem >> 3, jj = rem & 7;
            int ka = ks * 32 + ((jj >> 2) << 4) + q * 4 + (jj & 3);
            v = eW2[ka * H_NF + n];
        }
        w2h[j] = (_Float16)v;
    } else if (i < SEG3) {
        int j = i - SEG2;
        int n = j / K1N, k = j - n * K1N;
        float v = 0.f;
        if (k < 11)                  v = nW1[k * H_NF + n];
        else if (k >= 12 && k < 140) v = nW1[(k - 1) * H_NF + n];
        w1nh[j] = (_Float16)v;
    } else if (i < SEG4) {
        int j = i - SEG3;
        if (j < 16 * K2P) {
            int n = j / K2P, k = j - n * K2P;
            float v = 0.f;
            if (n < 4 && k < H_NF) {
                for (int q = 0; q < H_NF; ++q) v += nW2[k * H_NF + q] * fW[q * 4 + n];
            }
            w23h[j] = (_Float16)v;
        } else {
            int o = j - 16 * K2P;
            float v = fb[o];
            for (int q = 0; q < H_NF; ++q) v += nb2[q] * fW[q * 4 + o];
            b23[o] = v;
        }
    } else if (i < SEG5) {
        int e = i - SEG4;
        atomicAdd(&hist[edge_index[e]], 1);
    }
}

__global__ __launch_bounds__(256)
void transpose_w2(const float* __restrict__ W, float* __restrict__ WT) {
    int i = blockIdx.x * 256 + threadIdx.x;
    if (i < H_NF * H_NF) {
        int k = i >> 7, j = i & (H_NF - 1);
        WT[j * H_NF + k] = W[i];
    }
}

// ---------------------------------------------------------------------------
// Scan chain.
// ---------------------------------------------------------------------------
__global__ __launch_bounds__(SCAN_B)
void scan1_kernel(const int* __restrict__ hist, int* starts, int* bsum) {
    __shared__ int buf[SCAN_B];
    int i = blockIdx.x * SCAN_B + threadIdx.x;
    int v = (i < N_NODES) ? hist[i] : 0;
    buf[threadIdx.x] = v;
    __syncthreads();
    for (int off = 1; off < SCAN_B; off <<= 1) {
        int t = (threadIdx.x >= off) ? buf[threadIdx.x - off] : 0;
        __syncthreads();
        buf[threadIdx.x] += t;
        __syncthreads();
    }
    if (i < N_NODES) starts[i] = buf[threadIdx.x] - v;
    if (threadIdx.x == SCAN_B - 1) bsum[blockIdx.x] = buf[SCAN_B - 1];
}

__global__ void scan2_kernel(int* bsum) {
    if (threadIdx.x == 0 && blockIdx.x == 0) {
        int run = 0;
        for (int b = 0; b < NBLK; ++b) { int t = bsum[b]; bsum[b] = run; run += t; }
        bsum[NBLK] = run;
    }
}

__global__ __launch_bounds__(256)
void scan3_kernel(int* starts, int* cursor, const int* __restrict__ bsum) {
    int i = blockIdx.x * 256 + threadIdx.x;
    if (i < N_NODES) {
        int s = starts[i] + bsum[i / SCAN_B];
        starts[i] = s;
        cursor[i] = s;
    }
    if (i == 0) starts[N_NODES] = bsum[NBLK];
}

// ---------------------------------------------------------------------------
// Permute into 16B records: rec[pos] = {row, col, attr01, attr23}.
// ---------------------------------------------------------------------------
__global__ __launch_bounds__(256)
void permrec_kernel(const int* __restrict__ edge_index,
                    const float* __restrict__ edge_attr,
                    int* cursor,
                    int4* __restrict__ rec)
{
    int e = blockIdx.x * 256 + threadIdx.x;
    if (e >= N_EDGES) return;
    int row = edge_index[e];
    int col = edge_index[N_EDGES + e];
    float4 a4 = ((const float4*)edge_attr)[e];
    union { _Float16 h[4]; int2 v; } u;
    u.h[0] = (_Float16)a4.x; u.h[1] = (_Float16)a4.y;
    u.h[2] = (_Float16)a4.z; u.h[3] = (_Float16)a4.w;
    int pos = atomicAdd(&cursor[row], 1);
    rec[pos] = make_int4(row, col, u.v.x, u.v.y);
}

// Tier-2: classic permute (perm only).
__global__ __launch_bounds__(256)
void permute_kernel(const int* __restrict__ edge_index, int* cursor, int* perm) {
    int e = blockIdx.x * 256 + threadIdx.x;
    if (e < N_EDGES) {
        int pos = atomicAdd(&cursor[edge_index[e]], 1);
        perm[pos] = e;
    }
}

// ---------------------------------------------------------------------------
// Edge MLP v7b: register-only MLP. Zero LDS, zero barriers, zero transpose.
//  - layer 1 computed OPERAND-SWAPPED: mfma(W1, X) (A/B fragment lane layouts
//    are identical). D layout: lane (m,q) holds H[edge m][16*tile + 4*q + r].
//  - layer-1 bias planted in w1h at k=28, 1.0 in the input k=28 slot.
//  - layer-2 k-axis PERMUTED (baked into w2h at prep): k_actual(ks,q,j) =
//    32ks + 16*(j>>2) + 4q + (j&3). Under this permutation the layer-2
//    A-fragment is exactly the lane's own layer-1 output registers:
//    a2[ks] = {hx[2ks], hy[2ks], hx[2ks+1], hy[2ks+1]} — pure reinterpret.
//    (Legal: sum over k is permutation-invariant when BOTH operands use the
//    same k ordering, and both A/B fragments index k by the same (ks,q,j).)
//  - layer-1 input fragment built from prefetched gather regs via 6 shfls.
// W2 stays in registers; 2 waves/SIMD by design (v6 proved occupancy is not
// the lever; per-window work and LDS chains were).
// ---------------------------------------------------------------------------
__global__ __launch_bounds__(256, 2)
void edge_mfma_kernel(const int4* __restrict__ recs,
                      const _Float16* __restrict__ nfh,
                      const _Float16* __restrict__ w1h,
                      const _Float16* __restrict__ w2h,
                      const float* __restrict__ eb2,
                      float* agg)   // [N_NODES][H_NF]
{
    int t = threadIdx.x;
    int wv = t >> 6, lane = t & 63;
    int m = lane & 15, quad = lane >> 4;

    // loop-invariant weight fragments -> registers
    half8 w1f[8], w2f[8][4];
    #pragma unroll
    for (int tile = 0; tile < 8; ++tile)
        w1f[tile] = *(const half8*)(w1h + (tile * 16 + m) * K1P + quad * 8);
    #pragma unroll
    for (int tile = 0; tile < 8; ++tile)
        #pragma unroll
        for (int ks = 0; ks < 4; ++ks)
            w2f[tile][ks] = *(const half8*)(w2h + (tile * 16 + m) * K2P + ks * 32 + quad * 8);
    float b2v[8];
    #pragma unroll
    for (int tile = 0; tile < 8; ++tile)
        b2v[tile] = eb2[tile * 16 + m];

    const int nwin = N_EDGES / 16;           // 100000
    const int STRIDE = gridDim.x * 4;
    int win = blockIdx.x * 4 + wv;
    if (win >= nwin) return;

    // preamble: rec + nfh gather for the first window
    int4 rc = recs[win * 16 + m];            // 16 unique 16B addrs, L1-broadcast
    int2 g0 = make_int2(0, 0), g1 = g0, g2 = g0;
    if (quad < 2) {
        int node = (quad == 0) ? rc.x : rc.y;
        const int2* p = (const int2*)(nfh + (size_t)node * 12);
        g0 = p[0]; g1 = p[1]; g2 = p[2];
    }

    while (true) {
        int next = win + STRIDE;
        bool hn = next < nwin;
        int4 rcn = make_int4(0, 0, 0, 0);
        if (hn) rcn = recs[next * 16 + m];   // prefetch rec for next window

        // ---- build layer-1 B-fragment (edge m, k=quad*8..+7) in registers --
        // q0: src[0..7]            = {g0.x,g0.y,g1.x,g1.y}       (own, quad0)
        // q1: src[8..11],dst[0..3] = {q0's g2, own g0}
        // q2: dst[4..11]           = {q1's g1, q1's g2}
        // q3: attr[0..3],1.0,0,0,0 = {rc.z, rc.w, 0x3C00, 0}
        int sAx = __shfl(g2.x, m),      sAy = __shfl(g2.y, m);        // quad0 g2
        int sBx = __shfl(g1.x, m + 16), sBy = __shfl(g1.y, m + 16);   // quad1 g1
        int sCx = __shfl(g2.x, m + 16), sCy = __shfl(g2.y, m + 16);   // quad1 g2
        int d0 = (quad == 0) ? g0.x : (quad == 1) ? sAx : (quad == 2) ? sBx : rc.z;
        int d1 = (quad == 0) ? g0.y : (quad == 1) ? sAy : (quad == 2) ? sBy : rc.w;
        int d2 = (quad == 0) ? g1.x : (quad == 1) ? g0.x : (quad == 2) ? sCx : 0x00003C00;
        int d3 = (quad == 0) ? g1.y : (quad == 1) ? g0.y : (quad == 2) ? sCy : 0;
        union { int i[4]; half8 h; } ua;
        ua.i[0] = d0; ua.i[1] = d1; ua.i[2] = d2; ua.i[3] = d3;
        half8 a1 = ua.h;

        // ---- layer 1 swapped: lane (m,q) -> H[m][16*tile+4q+r], relu+pack.
        // Tile t's packed dwords land directly in a2[t>>1] (permuted k-axis).
        union { unsigned u[4]; half8 h; } ua2[4];
        #pragma unroll
        for (int tile = 0; tile < 8; ++tile) {
            floatx4 c = {0.f, 0.f, 0.f, 0.f};
            c = __builtin_amdgcn_mfma_f32_16x16x32_f16(w1f[tile], a1, c, 0, 0, 0);
            union { _Float16 f[2]; unsigned u; } p0, p1;
            p0.f[0] = (_Float16)fmaxf(c[0], 0.f);
            p0.f[1] = (_Float16)fmaxf(c[1], 0.f);
            p1.f[0] = (_Float16)fmaxf(c[2], 0.f);
            p1.f[1] = (_Float16)fmaxf(c[3], 0.f);
            ua2[tile >> 1].u[(tile & 1) * 2 + 0] = p0.u;
            ua2[tile >> 1].u[(tile & 1) * 2 + 1] = p1.u;
        }

        // ---- layer 2: 128 -> 128 over permuted k, values in regs (C-layout)
        float vals[32];
        #pragma unroll
        for (int tile = 0; tile < 8; ++tile) {
            floatx4 c = {0.f, 0.f, 0.f, 0.f};
            #pragma unroll
            for (int ks = 0; ks < 4; ++ks)
                c = __builtin_amdgcn_mfma_f32_16x16x32_f16(ua2[ks].h, w2f[tile][ks], c, 0, 0, 0);
            #pragma unroll
            for (int r = 0; r < 4; ++r)
                vals[tile * 4 + r] = fmaxf(c[r] + b2v[tile], 0.f);
        }

        // ---- pipelined nfh gather for next window (rcn has arrived) ----
        int2 n0 = make_int2(0, 0), n1 = n0, n2 = n0;
        if (hn && quad < 2) {
            int node = (quad == 0) ? rcn.x : rcn.y;
            const int2* p = (const int2*)(nfh + (size_t)node * 12);
            n0 = p[0]; n1 = p[1]; n2 = p[2];
        }

        // ---- segmented reduction, rows via shuffles from rc.x ----
        int row = rc.x;                           // row of edge m (all quads)
        int rprev = __shfl(row, lane - 1);
        bool bi = (lane < 16) && (m == 0 || rprev != row);
        unsigned long long bm = __ballot(bi);
        unsigned mk = (unsigned)(bm & 0xFFFFull); // wave-uniform segment starts
        int er0 = __shfl(row, quad * 4 + 0);
        int er1 = __shfl(row, quad * 4 + 1);
        int er2 = __shfl(row, quad * 4 + 2);
        int er3 = __shfl(row, quad * 4 + 3);
        while (mk) {
            int start = __builtin_ctz(mk);        // wave-uniform
            mk &= mk - 1;
            int srow = __shfl(row, start);
            float s[8];
            #pragma unroll
            for (int tile = 0; tile < 8; ++tile) {
                float v = 0.f;
                if (er0 == srow) v += vals[tile * 4 + 0];
                if (er1 == srow) v += vals[tile * 4 + 1];
                if (er2 == srow) v += vals[tile * 4 + 2];
                if (er3 == srow) v += vals[tile * 4 + 3];
                s[tile] = v;
            }
            #pragma unroll
            for (int tile = 0; tile < 8; ++tile) {
                s[tile] += __shfl_xor(s[tile], 16);
                s[tile] += __shfl_xor(s[tile], 32);
            }
            if (quad == 0) {
                #pragma unroll
                for (int tile = 0; tile < 8; ++tile)
                    unsafeAtomicAdd(&agg[(size_t)srow * H_NF + tile * 16 + m], s[tile]);
            }
        }

        if (!hn) break;
        win = next; rc = rcn; g0 = n0; g1 = n1; g2 = n2;
    }
}

// ---------------------------------------------------------------------------
// Tier-2 edge kernel: in-kernel gather via perm (no rec buffer). LDS reduction.
// w2h is k-PERMUTED, so the a2 read from Hs uses the permuted offsets:
// a2[ks] = Hs[m][32ks+4q+0..3] ++ Hs[m][32ks+16+4q+0..3] (two b64 reads).
// (w1h's k=28 bias slot multiplies its zeroed k28 input -> explicit b1v add
// here remains correct.)
// ---------------------------------------------------------------------------
#define G_W1      0
#define G_W2      10240
#define G_ARENA   45056
#define G_ARENA_SZ 8448
#define G_TOTAL   (G_ARENA + 4 * G_ARENA_SZ)

__global__ __launch_bounds__(256, 2)
void edge_mfma_gather_kernel(const _Float16* __restrict__ nfh,
                             const int*   __restrict__ edge_index,
                             const float* __restrict__ edge_attr,
                             const _Float16* __restrict__ w1h,
                             const float* __restrict__ eb1,
                             const _Float16* __restrict__ w2h,
                             const float* __restrict__ eb2,
                             const int*   __restrict__ perm,
                             float* agg)
{
    __shared__ __align__(16) char smem[G_TOTAL];
    _Float16* W1s = (_Float16*)(smem + G_W1);
    _Float16* W2s = (_Float16*)(smem + G_W2);
    int t = threadIdx.x;
    {
        const float4* g1 = (const float4*)w1h;
        float4* s1 = (float4*)W1s;
        for (int i = t; i < 640; i += 256) s1[i] = g1[i];
        const float4* g2 = (const float4*)w2h;
        float4* s2 = (float4*)W2s;
        for (int i = t; i < 2176; i += 256) s2[i] = g2[i];
    }
    __syncthreads();

    int wv = t >> 6, lane = t & 63;
    char* arena = smem + G_ARENA + wv * G_ARENA_SZ;
    _Float16* Ain  = (_Float16*)arena;
    _Float16* Hs   = (_Float16*)(arena + 1280);
    float*    efS  = (float*)arena;
    int*      rowsS = (int*)(arena + 8384);

    int m = lane & 15, quad = lane >> 4;
    int el = lane & 15, grp = lane >> 4;
    _Float16* arow = Ain + el * K1P;

    float b1v[8], b2v[8];
    #pragma unroll
    for (int tile = 0; tile < 8; ++tile) {
        b1v[tile] = eb1[tile * 16 + m];
        b2v[tile] = eb2[tile * 16 + m];
    }

    const int nwin = N_EDGES / 16;
    for (int win = blockIdx.x * 4 + wv; win < nwin; win += gridDim.x * 4) {
        int e = perm[win * 16 + el];
        if (grp < 2) {
            int node = edge_index[grp * N_EDGES + e];
            const int2* p = (const int2*)(nfh + (size_t)node * 12);
            int2 x0 = p[0], x1 = p[1], x2 = p[2];
            char* dst = (char*)(arow + grp * 12);
            *(int2*)(dst) = x0; *(int2*)(dst + 8) = x1; *(int2*)(dst + 16) = x2;
        } else if (grp == 2) {
            float4 a4 = ((const float4*)edge_attr)[e];
            arow[24] = (_Float16)a4.x; arow[25] = (_Float16)a4.y;
            arow[26] = (_Float16)a4.z; arow[27] = (_Float16)a4.w;
        } else {
            rowsS[el] = edge_index[e];
            *(int2*)((char*)arow + 56) = make_int2(0, 0);
        }

        half8 a1 = *(const half8*)(Ain + m * K1P + quad * 8);
        #pragma unroll
        for (int tile = 0; tile < 8; ++tile) {
            half8 b = *(const half8*)(W1s + (tile * 16 + m) * K1P + quad * 8);
            floatx4 c = {0.f, 0.f, 0.f, 0.f};
            c = __builtin_amdgcn_mfma_f32_16x16x32_f16(a1, b, c, 0, 0, 0);
            int n = tile * 16 + m;
            #pragma unroll
            for (int r = 0; r < 4; ++r)
                Hs[(quad * 4 + r) * K2P + n] = (_Float16)fmaxf(c[r] + b1v[tile], 0.f);
        }
        half8 a2[4];
        #pragma unroll
        for (int ks = 0; ks < 4; ++ks) {
            const _Float16* hp = Hs + m * K2P + ks * 32 + quad * 4;
            union { int2 d[2]; half8 h; } uu;
            uu.d[0] = *(const int2*)(hp);
            uu.d[1] = *(const int2*)(hp + 16);
            a2[ks] = uu.h;
        }
        #pragma unroll
        for (int tile = 0; tile < 8; ++tile) {
            floatx4 c = {0.f, 0.f, 0.f, 0.f};
            #pragma unroll
            for (int ks = 0; ks < 4; ++ks) {
                half8 b = *(const half8*)(W2s + (tile * 16 + m) * K2P + ks * 32 + quad * 8);
                c = __builtin_amdgcn_mfma_f32_16x16x32_f16(a2[ks], b, c, 0, 0, 0);
            }
            #pragma unroll
            for (int r = 0; r < 4; ++r)
                efS[(quad * 4 + r) * EFP + tile * 16 + m] = fmaxf(c[r] + b2v[tile], 0.f);
        }

        int f = lane;
        int cur = rowsS[0];
        float acc0 = efS[f], acc1 = efS[64 + f];
        #pragma unroll 1
        for (int i = 1; i < 16; ++i) {
            int r = rowsS[i];
            float v0 = efS[i * EFP + f];
            float v1 = efS[i * EFP + 64 + f];
            if (r != cur) {
                unsafeAtomicAdd(&agg[(size_t)cur * H_NF + f], acc0);
                unsafeAtomicAdd(&agg[(size_t)cur * H_NF + 64 + f], acc1);
                acc0 = v0; acc1 = v1; cur = r;
            } else { acc0 += v0; acc1 += v1; }
        }
        unsafeAtomicAdd(&agg[(size_t)cur * H_NF + f], acc0);
        unsafeAtomicAdd(&agg[(size_t)cur * H_NF + 64 + f], acc1);
    }
}

// ---------------------------------------------------------------------------
// Fused node pipeline, persistent, epilogue bias.
// ---------------------------------------------------------------------------
#define N_W1    0                         // 128*160*2 = 40960
#define N_W23   40960                     // 16*136*2  = 4352 -> 45312
#define N_HS    45312                     // + 4*4352 -> 62720

__global__ __launch_bounds__(256, 2)
void node_mfma_kernel(const float* __restrict__ node_feats,
                      const float* __restrict__ agg,
                      const _Float16* __restrict__ w1nh,
                      const float* __restrict__ nb1,
                      const _Float16* __restrict__ w23h,
                      const float* __restrict__ b23,
                      float* __restrict__ out)
{
    __shared__ __align__(16) char smem[N_HS + 4 * 4352];
    _Float16* W1N  = (_Float16*)(smem + N_W1);
    _Float16* W23s = (_Float16*)(smem + N_W23);
    int t = threadIdx.x;
    {
        const float4* g1 = (const float4*)w1nh;
        float4* s1 = (float4*)W1N;
        for (int i = t; i < 2560; i += 256) s1[i] = g1[i];
        const float4* g2 = (const float4*)w23h;
        float4* s2 = (float4*)W23s;
        for (int i = t; i < 272; i += 256) s2[i] = g2[i];
    }
    __syncthreads();

    int wv = t >> 6, lane = t & 63;
    int m = lane & 15, quad = lane >> 4;
    _Float16* HsW = (_Float16*)(smem + N_HS + wv * 4352);
    const int ntile = (N_NODES + 63) / 64;   // 1563

    float nb1v[8];
    #pragma unroll
    for (int tile = 0; tile < 8; ++tile) nb1v[tile] = nb1[tile * 16 + m];
    float b23v = (m < 4) ? b23[m] : 0.f;

    for (int ti = blockIdx.x; ti < ntile; ti += gridDim.x) {
        int nb = (ti * 4 + wv) * 16;
        if (nb >= N_NODES) continue;
        int nodeA = nb + m;
        if (nodeA >= N_NODES) nodeA = N_NODES - 1;
        const float* ag  = agg + (size_t)nodeA * H_NF;
        const float* nfp = node_feats + (size_t)nodeA * NODE_NF;

        half8 afr[5];
        if (quad == 0) {
            half8 r;
            #pragma unroll
            for (int j = 0; j < 8; ++j) r[j] = (_Float16)nfp[j];
            afr[0] = r;
            afr[4] = load8f(ag + 116);
        } else if (quad == 1) {
            half8 r;
            r[0] = (_Float16)nfp[8]; r[1] = (_Float16)nfp[9];
            r[2] = (_Float16)nfp[10]; r[3] = (_Float16)0.f;
            float4 x = *(const float4*)(ag);
            r[4] = (_Float16)x.x; r[5] = (_Float16)x.y;
            r[6] = (_Float16)x.z; r[7] = (_Float16)x.w;
            afr[0] = r;
            float4 y = *(const float4*)(ag + 124);
            half8 s = zero8();
            s[0] = (_Float16)y.x; s[1] = (_Float16)y.y;
            s[2] = (_Float16)y.z; s[3] = (_Float16)y.w;
            afr[4] = s;
        } else if (quad == 2) {
            afr[0] = load8f(ag + 4);
            afr[4] = zero8();
        } else {
            afr[0] = load8f(ag + 12);
            afr[4] = zero8();
        }
        afr[1] = load8f(ag + 20 + 8 * quad);
        afr[2] = load8f(ag + 52 + 8 * quad);
        afr[3] = load8f(ag + 84 + 8 * quad);

        #pragma unroll
        for (int tile = 0; tile < 8; ++tile) {
            floatx4 c = {0.f, 0.f, 0.f, 0.f};
            #pragma unroll
            for (int ks = 0; ks < 5; ++ks) {
                half8 b = *(const half8*)(W1N + (tile * 16 + m) * K1N + ks * 32 + quad * 8);
                c = __builtin_amdgcn_mfma_f32_16x16x32_f16(afr[ks], b, c, 0, 0, 0);
            }
            #pragma unroll
            for (int r = 0; r < 4; ++r)
                HsW[(quad * 4 + r) * K2P + tile * 16 + m] = (_Float16)fmaxf(c[r] + nb1v[tile], 0.f);
        }

        half8 a2[4];
        #pragma unroll
        for (int ks = 0; ks < 4; ++ks)
            a2[ks] = *(const half8*)(HsW + m * K2P + ks * 32 + quad * 8);
        floatx4 c23 = {0.f, 0.f, 0.f, 0.f};
        #pragma unroll
        for (int ks = 0; ks < 4; ++ks) {
            half8 b = *(const half8*)(W23s + m * K2P + ks * 32 + quad * 8);
            c23 = __builtin_amdgcn_mfma_f32_16x16x32_f16(a2[ks], b, c23, 0, 0, 0);
        }
        if (m < 4) {
            #pragma unroll
            for (int r = 0; r < 4; ++r) {
                int node = nb + quad * 4 + r;
                if (node < N_NODES) out[node * 4 + m] = c23[r] + b23v;
            }
        }
    }
}

// ---------------------------------------------------------------------------
// Tier-3 fp32 fallback.
// ---------------------------------------------------------------------------
__global__ __launch_bounds__(256)
void edge_kernel_atomic(const float* __restrict__ node_feats,
                        const int*   __restrict__ edge_index,
                        const float* __restrict__ edge_attr,
                        const float* __restrict__ eW1,
                        const float* __restrict__ eb1,
                        const float* __restrict__ W2T,
                        const float* __restrict__ eb2,
                        float* agg)
{
    int e = blockIdx.x * 256 + threadIdx.x;
    if (e >= N_EDGES) return;
    int row = edge_index[e];
    int col = edge_index[N_EDGES + e];
    float h[H_NF];
    #pragma unroll
    for (int j = 0; j < H_NF; ++j) h[j] = eb1[j];
    const float* srcp = node_feats + (size_t)row * NODE_NF;
    #pragma unroll 1
    for (int k = 0; k < NODE_NF; ++k) {
        float x = srcp[k];
        const float* w = eW1 + k * H_NF;
        #pragma unroll
        for (int j = 0; j < H_NF; ++j) h[j] = fmaf(x, w[j], h[j]);
    }
    const float* dstp = node_feats + (size_t)col * NODE_NF;
    #pragma unroll 1
    for (int k = 0; k < NODE_NF; ++k) {
        float x = dstp[k];
        const float* w = eW1 + (NODE_NF + k) * H_NF;
        #pragma unroll
        for (int j = 0; j < H_NF; ++j) h[j] = fmaf(x, w[j], h[j]);
    }
    float4 at = ((const float4*)edge_attr)[e];
    float av[EDGE_NF] = {at.x, at.y, at.z, at.w};
    #pragma unroll
    for (int k = 0; k < EDGE_NF; ++k) {
        float x = av[k];
        const float* w = eW1 + (2 * NODE_NF + k) * H_NF;
        #pragma unroll
        for (int j = 0; j < H_NF; ++j) h[j] = fmaf(x, w[j], h[j]);
    }
    #pragma unroll
    for (int j = 0; j < H_NF; ++j) h[j] = fmaxf(h[j], 0.f);
    #pragma unroll 1
    for (int j0 = 0; j0 < H_NF; j0 += 8) {
        float acc[8];
        #pragma unroll
        for (int jj = 0; jj < 8; ++jj) acc[jj] = eb2[j0 + jj];
        #pragma unroll
        for (int k = 0; k < H_NF; ++k) {
            float x = h[k];
            #pragma unroll
            for (int jj = 0; jj < 8; ++jj)
                acc[jj] = fmaf(x, W2T[(j0 + jj) * H_NF + k], acc[jj]);
        }
        #pragma unroll
        for (int jj = 0; jj < 8; ++jj)
            unsafeAtomicAdd(&agg[(size_t)row * H_NF + j0 + jj], fmaxf(acc[jj], 0.f));
    }
}

__global__ __launch_bounds__(256)
void node_kernel1(const float* __restrict__ node_feats, float* agg_nh,
                  const float* __restrict__ nW1, const float* __restrict__ nb1)
{
    int n = blockIdx.x * 256 + threadIdx.x;
    if (n >= N_NODES) return;
    float acc[H_NF];
    #pragma unroll
    for (int j = 0; j < H_NF; ++j) acc[j] = nb1[j];
    const float* nfp = node_feats + (size_t)n * NODE_NF;
    #pragma unroll 1
    for (int k = 0; k < NODE_NF; ++k) {
        float x = nfp[k];
        const float* w = nW1 + k * H_NF;
        #pragma unroll
        for (int j = 0; j < H_NF; ++j) acc[j] = fmaf(x, w[j], acc[j]);
    }
    const float4* ap = (const float4*)(agg_nh + (size_t)n * H_NF);
    #pragma unroll 1
    for (int k4 = 0; k4 < H_NF / 4; ++k4) {
        float4 x = ap[k4];
        const float* w0 = nW1 + (NODE_NF + k4 * 4 + 0) * H_NF;
        const float* w1 = nW1 + (NODE_NF + k4 * 4 + 1) * H_NF;
        const float* w2 = nW1 + (NODE_NF + k4 * 4 + 2) * H_NF;
        const float* w3 = nW1 + (NODE_NF + k4 * 4 + 3) * H_NF;
        #pragma unroll
        for (int j = 0; j < H_NF; ++j) {
            acc[j] = fmaf(x.x, w0[j], acc[j]);
            acc[j] = fmaf(x.y, w1[j], acc[j]);
            acc[j] = fmaf(x.z, w2[j], acc[j]);
            acc[j] = fmaf(x.w, w3[j], acc[j]);
        }
    }
    float* op = agg_nh + (size_t)n * H_NF;
    #pragma unroll
    for (int j4 = 0; j4 < H_NF / 4; ++j4) {
        float4 o = make_float4(fmaxf(acc[j4*4+0], 0.f), fmaxf(acc[j4*4+1], 0.f),
                               fmaxf(acc[j4*4+2], 0.f), fmaxf(acc[j4*4+3], 0.f));
        ((float4*)op)[j4] = o;
    }
}

__global__ __launch_bounds__(256)
void node_kernel2(const float* __restrict__ nh, const float* __restrict__ nW2,
                  const float* __restrict__ nb2, const float* __restrict__ fW,
                  const float* __restrict__ fb, float* __restrict__ out)
{
    int n = blockIdx.x * 256 + threadIdx.x;
    if (n >= N_NODES) return;
    float acc[H_NF];
    #pragma unroll
    for (int j = 0; j < H_NF; ++j) acc[j] = nb2[j];
    const float4* hp = (const float4*)(nh + (size_t)n * H_NF);
    #pragma unroll 1
    for (int k4 = 0; k4 < H_NF / 4; ++k4) {
        float4 x = hp[k4];
        const float* w0 = nW2 + (k4 * 4 + 0) * H_NF;
        const float* w1 = nW2 + (k4 * 4 + 1) * H_NF;
        const float* w2 = nW2 + (k4 * 4 + 2) * H_NF;
        const float* w3 = nW2 + (k4 * 4 + 3) * H_NF;
        #pragma unroll
        for (int j = 0; j < H_NF; ++j) {
            acc[j] = fmaf(x.x, w0[j], acc[j]);
            acc[j] = fmaf(x.y, w1[j], acc[j]);
            acc[j] = fmaf(x.z, w2[j], acc[j]);
            acc[j] = fmaf(x.w, w3[j], acc[j]);
        }
    }
    float o0 = fb[0], o1 = fb[1], o2 = fb[2], o3 = fb[3];
    #pragma unroll
    for (int j = 0; j < H_NF; ++j) {
        o0 = fmaf(acc[j], fW[j * 4 + 0], o0);
        o1 = fmaf(acc[j], fW[j * 4 + 1], o1);
        o2 = fmaf(acc[j], fW[j * 4 + 2], o2);
        o3 = fmaf(acc[j], fW[j * 4 + 3], o3);
    }
    ((float4*)out)[n] = make_float4(o0, o1, o2, o3);
}

extern "C" void kernel_launch(void* const* d_in, const int* in_sizes, int n_in,
                              void* d_out, int out_size, void* d_ws, size_t ws_size,
                              hipStream_t stream)
{
    const float* node_feats = (const float*)d_in[0];
    const int*   edge_index = (const int*)d_in[1];
    const float* edge_attr  = (const float*)d_in[2];
    const float* eW1 = (const float*)d_in[3];
    const float* eb1 = (const float*)d_in[4];
    const float* eW2 = (const float*)d_in[5];
    const float* eb2 = (const float*)d_in[6];
    const float* nW1 = (const float*)d_in[7];
    const float* nb1 = (const float*)d_in[8];
    const float* nW2 = (const float*)d_in[9];
    const float* nb2 = (const float*)d_in[10];
    const float* fW  = (const float*)d_in[11];
    const float* fb  = (const float*)d_in[12];
    float* out = (float*)d_out;

    // ---- workspace carve-up (256B aligned). agg+hist adjacent -> ONE memset.
    size_t off = 0;
    auto carve = [&](size_t bytes) {
        void* p = (char*)d_ws + off;
        off = (off + bytes + 255) & ~(size_t)255;
        return p;
    };
    float*     agg    = (float*)carve((size_t)N_NODES * H_NF * sizeof(float)); // 51.2 MB
    int*       hist   = (int*)  carve((size_t)N_NODES * sizeof(int));
    size_t zero_bytes = off;   // agg + hist (contiguous from d_ws base)
    int*       starts = (int*)  carve((size_t)(N_NODES + 1) * sizeof(int));
    int*       cursor = (int*)  carve((size_t)N_NODES * sizeof(int));
    int*       bsum   = (int*)  carve((size_t)(NBLK + 1) * sizeof(int));
    _Float16*  nfh    = (_Float16*)carve((size_t)N_NODES * 12 * sizeof(_Float16)); // 2.4 MB
    _Float16*  w1h    = (_Float16*)carve((size_t)H_NF * K1P * sizeof(_Float16));
    _Float16*  w2h    = (_Float16*)carve((size_t)H_NF * K2P * sizeof(_Float16));
    _Float16*  w1nh   = (_Float16*)carve((size_t)H_NF * K1N * sizeof(_Float16));
    _Float16*  w23h   = (_Float16*)carve((size_t)16 * K2P * sizeof(_Float16));
    float*     b23    = (float*)carve(4 * sizeof(float));
    int*       perm   = (int*)  carve((size_t)N_EDGES * sizeof(int));          // tier-2 only
    size_t required_t2 = off;
    int4*      rec    = (int4*) carve((size_t)N_EDGES * sizeof(int4));         // 25.6 MB
    size_t required_t1 = off;

    if (ws_size >= required_t2) {
        hipMemsetAsync(d_ws, 0, zero_bytes, stream);
        prep_hist_kernel<<<(SEG5 + 255) / 256, 256, 0, stream>>>(
            node_feats, eW1, eb1, eW2, nW1, nW2, fW, nb2, fb, edge_index,
            nfh, w1h, w2h, w1nh, w23h, b23, hist);
        scan1_kernel<<<NBLK, SCAN_B, 0, stream>>>(hist, starts, bsum);
        scan2_kernel<<<1, 64, 0, stream>>>(bsum);
        scan3_kernel<<<(N_NODES + 255) / 256, 256, 0, stream>>>(starts, cursor, bsum);

        if (ws_size >= required_t1) {
            permrec_kernel<<<(N_EDGES + 255) / 256, 256, 0, stream>>>(
                edge_index, edge_attr, cursor, rec);
            edge_mfma_kernel<<<512, 256, 0, stream>>>(
                rec, nfh, w1h, w2h, eb2, agg);
        } else {
            permute_kernel<<<(N_EDGES + 255) / 256, 256, 0, stream>>>(edge_index, cursor, perm);
            edge_mfma_gather_kernel<<<512, 256, 0, stream>>>(
                nfh, edge_index, edge_attr, w1h, eb1, w2h, eb2, perm, agg);
        }
        node_mfma_kernel<<<512, 256, 0, stream>>>(
            node_feats, agg, w1nh, nb1, w23h, b23, out);
    } else {
        // tier 3: fp32 atomic scatter path
        float* agg_fb = (float*)d_ws;
        float* W2T_fb = (float*)((char*)d_ws + (size_t)N_NODES * H_NF * sizeof(float));
        transpose_w2<<<(H_NF * H_NF + 255) / 256, 256, 0, stream>>>(eW2, W2T_fb);
        hipMemsetAsync(agg_fb, 0, (size_t)N_NODES * H_NF * sizeof(float), stream);
        edge_kernel_atomic<<<(N_EDGES + 255) / 256, 256, 0, stream>>>(
            node_feats, edge_index, edge_attr, eW1, eb1, W2T_fb, eb2, agg_fb);
        node_kernel1<<<(N_NODES + 255) / 256, 256, 0, stream>>>(node_feats, agg_fb, nW1, nb1);
        node_kernel2<<<(N_NODES + 255) / 256, 256, 0, stream>>>(agg_fb, nW2, nb2, fW, fb, out);
    }
}